// Round 1
// baseline (265.544 us; speedup 1.0000x reference)
//
#include <hip/hip_runtime.h>
#include <math.h>

// BERT-CRF forward NLL on MI355X.
// Exp-domain forward recursion: alpha[b,j] = c[b]*ln2 + log(p[b,j]).
// Per step: q[j] = sum_i p[i]*E[i][j]  (E = exp(trans), column j in VGPRs),
// then p <- q * 2^-k * exp(feat), c += k with k = biased-exponent(q[0]).
// Lane j = tag j; one item per 32-lane half; 2 items per wave; block=64.
// Gold score fused into the same loop.

constexpr int NTAG   = 32;
constexpr int TSTART = 30;
constexpr int TSTOP  = 31;
constexpr int NB     = 1024;
constexpr int NS     = 512;
constexpr int PD     = 8;   // prefetch depth

__global__ __launch_bounds__(64)
void crf_fwd(const float* __restrict__ feats,
             const int*   __restrict__ labels,
             const int*   __restrict__ lengths,
             const float* __restrict__ trans,
             float*       __restrict__ out)
{
    __shared__ __align__(16) float s_p[2][NTAG];   // per-half p vector
    __shared__ float s_trans[NTAG * NTAG];

    const int tid  = threadIdx.x;
    const int half = tid >> 5;
    const int j    = tid & 31;
    const int b    = (blockIdx.x << 1) + half;

    // stage trans into LDS (coalesced)
    for (int k = tid; k < NTAG * NTAG; k += 64)
        s_trans[k] = trans[k];

    // E column j: E[i][j] = exp(trans[i][j]); exp(-10000) -> 0 handles the
    // banned transitions (column START, row STOP) automatically.
    float Ecol[NTAG];
    #pragma unroll
    for (int i = 0; i < NTAG; ++i)
        Ecol[i] = __expf(trans[i * NTAG + j]);

    const int len = lengths[b];
    const float* fb = feats  + (size_t)b * NS * NTAG;
    const int*   lb = labels + (size_t)b * NS;

    // t = 0
    float feat0 = fb[j];
    int   lab0  = lb[0];

    __syncthreads();   // s_trans ready

    float a0 = feat0 + s_trans[TSTART * NTAG + j];
    float p  = __expf(a0);
    s_p[half][j] = p;

    int   c        = 0;
    float emit     = __shfl(feat0, lab0, 32);          // feats[b,0,labels[b,0]]
    float pairs    = 0.0f;
    float start_sc = s_trans[TSTART * NTAG + lab0];
    int   lab_prev = lab0;
    int   lab_last = lab0;

    const int wl = max(len, __shfl_xor(len, 32, 64));  // max over the wave's 2 items

    // prefetch pipeline for feats/labels
    float pf[PD];
    int   pl[PD];
    #pragma unroll
    for (int d = 0; d < PD; ++d) {
        int tt = min(1 + d, NS - 1);
        pf[d] = fb[tt * NTAG + j];
        pl[d] = lb[tt];
    }

    const float4* pv4 = (const float4*)s_p[half];

    int t = 1;
    while (t < wl) {
        #pragma unroll
        for (int u = 0; u < PD; ++u) {
            if (t < wl) {   // wave-uniform predicate
                // keep compiler from moving LDS reads across the p store
                asm volatile("" ::: "memory");

                float feat = pf[u];
                int   lab  = pl[u];
                int   tn   = min(t + PD, NS - 1);
                pf[u] = fb[tn * NTAG + j];
                pl[u] = lb[tn];

                // q[j] = sum_i p[i] * E[i][j]; replicated p via 8x ds_read_b128
                float acc[4] = {0.f, 0.f, 0.f, 0.f};
                #pragma unroll
                for (int g = 0; g < 8; ++g) {
                    float4 pg = pv4[g];
                    float a = acc[g & 3];
                    a = fmaf(pg.x, Ecol[4 * g + 0], a);
                    a = fmaf(pg.y, Ecol[4 * g + 1], a);
                    a = fmaf(pg.z, Ecol[4 * g + 2], a);
                    a = fmaf(pg.w, Ecol[4 * g + 3], a);
                    acc[g & 3] = a;
                }
                float q = (acc[0] + acc[1]) + (acc[2] + acc[3]);

                // range normalization: k = exponent of q[0] (>0 always)
                float    q0   = __shfl(q, 0, 32);
                unsigned bits = __float_as_uint(q0);
                int      expo = (int)((bits >> 23) & 0xFF);
                expo = min(max(expo, 40), 215);               // safety clamp
                float scale = __uint_as_float((unsigned)(254 - expo) << 23); // 2^-k
                int   k     = expo - 127;

                float F  = __expf(feat);
                float pn = q * scale * F;

                bool upd = (t < len);
                p = upd ? pn : p;
                c = upd ? (c + k) : c;

                // gold-score terms (uniform within the half)
                float femit = __shfl(feat, lab, 32);          // feats[b,t,lab]
                float pr    = s_trans[lab_prev * NTAG + lab]; // trans[lab_{t-1},lab_t]
                emit     += upd ? femit : 0.f;
                pairs    += upd ? pr    : 0.f;
                lab_last  = upd ? lab   : lab_last;
                lab_prev  = lab;

                s_p[half][j] = p;
            }
            ++t;
        }
    }

    // forward score = c*ln2 + log(sum_j p[j])
    float s = p;
    #pragma unroll
    for (int m = 16; m > 0; m >>= 1)
        s += __shfl_xor(s, m, 32);
    float fwd = (float)c * 0.69314718055994530942f + __logf(s);

    float stop_sc = s_trans[lab_last * NTAG + TSTOP];
    float gold    = emit + start_sc + pairs + stop_sc;

    if (j == 0)
        atomicAdd(out, (fwd - gold) * (1.0f / 1024.0f));
}

extern "C" void kernel_launch(void* const* d_in, const int* in_sizes, int n_in,
                              void* d_out, int out_size, void* d_ws, size_t ws_size,
                              hipStream_t stream) {
    const float* feats   = (const float*)d_in[0];
    const int*   labels  = (const int*)d_in[1];
    const int*   lengths = (const int*)d_in[2];
    const float* trans   = (const float*)d_in[3];
    float*       out     = (float*)d_out;

    hipMemsetAsync(out, 0, sizeof(float) * (size_t)out_size, stream);
    crf_fwd<<<dim3(NB / 2), dim3(64), 0, stream>>>(feats, labels, lengths, trans, out);
}